// Round 1
// baseline (1404.831 us; speedup 1.0000x reference)
//
#include <hip/hip_runtime.h>

#define D 128

// out[i] = (1 + eps) * feat[i], vectorized float4
__global__ __launch_bounds__(256) void init_out_kernel(
    const float* __restrict__ feat, const float* __restrict__ eps,
    float* __restrict__ out, int n4) {
  int i = blockIdx.x * blockDim.x + threadIdx.x;
  if (i >= n4) return;
  float scale = 1.0f + eps[0];
  float4 v = ((const float4*)feat)[i];
  v.x *= scale; v.y *= scale; v.z *= scale; v.w *= scale;
  ((float4*)out)[i] = v;
}

// For each edge e: out[dst[e]][:] += feat[src[e]][:]
// 32 lanes per edge, float4 per lane (32*16B = 512B = one row)
__global__ __launch_bounds__(256) void scatter_add_kernel(
    const float* __restrict__ feat, const int* __restrict__ src,
    const int* __restrict__ dst, float* __restrict__ out, int E) {
  int gid = blockIdx.x * blockDim.x + threadIdx.x;
  int e = gid >> 5;
  int lane = gid & 31;
  if (e >= E) return;
  int s = src[e];
  int d = dst[e];
  float4 v = ((const float4*)(feat + (size_t)s * D))[lane];
  float* o = out + (size_t)d * D + lane * 4;
  unsafeAtomicAdd(o + 0, v.x);
  unsafeAtomicAdd(o + 1, v.y);
  unsafeAtomicAdd(o + 2, v.z);
  unsafeAtomicAdd(o + 3, v.w);
}

// In-place: out[row][:] = out_row @ W + b, tiled 64 rows per block.
// Each block reads its own 64 rows to LDS, computes, writes back same rows.
#define ROWS 64
__global__ __launch_bounds__(256) void gemm_inplace_kernel(
    float* __restrict__ out, const float* __restrict__ Wm,
    const float* __restrict__ bias, int N) {
  __shared__ float Ws[D * D];      // 64 KB
  __shared__ float xs[ROWS * D];   // 32 KB
  int tid = threadIdx.x;
  int base = blockIdx.x * ROWS;

  // stage W: 128*128 = 16384 floats = 4096 float4; 16 per thread
  #pragma unroll
  for (int it = 0; it < 16; ++it) {
    int idx = tid + 256 * it;
    ((float4*)Ws)[idx] = ((const float4*)Wm)[idx];
  }
  // stage x tile: 64*128 = 8192 floats = 2048 float4; 8 per thread
  #pragma unroll
  for (int it = 0; it < 8; ++it) {
    int idx = tid + 256 * it;
    int row = idx >> 5;      // 32 float4 per row
    int c4 = idx & 31;
    float4 v = make_float4(0.f, 0.f, 0.f, 0.f);
    if (base + row < N) v = ((const float4*)(out + (size_t)(base + row) * D))[c4];
    ((float4*)xs)[row * 32 + c4] = v;
  }
  __syncthreads();

  int tc = tid & 31;   // 32 col groups; cols = tc + 32*i (conflict-free W reads)
  int tr = tid >> 5;   // 8 row groups of 8 rows each
  float acc[8][4];
  #pragma unroll
  for (int r = 0; r < 8; ++r)
    #pragma unroll
    for (int i = 0; i < 4; ++i) acc[r][i] = 0.f;

  for (int k0 = 0; k0 < D; k0 += 4) {
    float4 f[8];
    #pragma unroll
    for (int r = 0; r < 8; ++r)
      f[r] = *(const float4*)&xs[(tr * 8 + r) * D + k0];
    float w[4][4];
    #pragma unroll
    for (int u = 0; u < 4; ++u)
      #pragma unroll
      for (int i = 0; i < 4; ++i)
        w[u][i] = Ws[(k0 + u) * D + tc + 32 * i];
    #pragma unroll
    for (int r = 0; r < 8; ++r)
      #pragma unroll
      for (int i = 0; i < 4; ++i) {
        acc[r][i] += f[r].x * w[0][i];
        acc[r][i] += f[r].y * w[1][i];
        acc[r][i] += f[r].z * w[2][i];
        acc[r][i] += f[r].w * w[3][i];
      }
  }

  float bv[4];
  #pragma unroll
  for (int i = 0; i < 4; ++i) bv[i] = bias[tc + 32 * i];

  #pragma unroll
  for (int r = 0; r < 8; ++r) {
    int row = base + tr * 8 + r;
    if (row < N) {
      #pragma unroll
      for (int i = 0; i < 4; ++i)
        out[(size_t)row * D + tc + 32 * i] = acc[r][i] + bv[i];
    }
  }
}

extern "C" void kernel_launch(void* const* d_in, const int* in_sizes, int n_in,
                              void* d_out, int out_size, void* d_ws, size_t ws_size,
                              hipStream_t stream) {
  const float* feat = (const float*)d_in[0];
  const float* Wm   = (const float*)d_in[1];
  const float* bias = (const float*)d_in[2];
  const float* eps  = (const float*)d_in[3];
  const int*   src  = (const int*)d_in[4];
  const int*   dst  = (const int*)d_in[5];
  float* out = (float*)d_out;

  int N = in_sizes[0] / D;   // 50000
  int E = in_sizes[4];       // 800000

  // 1. out = (1+eps)*feat
  int n4 = (N * D) / 4;
  init_out_kernel<<<(n4 + 255) / 256, 256, 0, stream>>>(feat, eps, out, n4);

  // 2. out[dst] += feat[src] (atomic scatter, 32 lanes/edge)
  long long total_threads = (long long)E * 32;
  int sblocks = (int)((total_threads + 255) / 256);
  scatter_add_kernel<<<sblocks, 256, 0, stream>>>(feat, src, dst, out, E);

  // 3. out = out @ W + b (in-place, row-tiled)
  int gblocks = (N + ROWS - 1) / ROWS;
  gemm_inplace_kernel<<<gblocks, 256, 0, stream>>>(out, Wm, bias, N);
}

// Round 2
// 206.787 us; speedup vs baseline: 6.7936x; 6.7936x over previous
//
#include <hip/hip_runtime.h>

#define D 128

// ---------------- CSR build path ----------------

__global__ __launch_bounds__(256) void hist_kernel(
    const int* __restrict__ dst, int* __restrict__ counts, int E) {
  int e = blockIdx.x * 256 + threadIdx.x;
  if (e < E) atomicAdd(&counts[dst[e]], 1);
}

// Block-wise exclusive scan; block base obtained via atomicAdd on a global
// counter. Bucket ranges are disjoint (all we need), though not ordered by
// node id -- summation-order nondeterminism only, well below threshold.
__global__ __launch_bounds__(256) void scan_kernel(
    const int* __restrict__ counts, int* __restrict__ start,
    int* __restrict__ cursor, int* __restrict__ gcount, int N) {
  __shared__ int tmp[256];
  __shared__ int base;
  int tid = threadIdx.x;
  int i = blockIdx.x * 256 + tid;
  int c = (i < N) ? counts[i] : 0;
  int val = c;
  tmp[tid] = val;
  __syncthreads();
  #pragma unroll
  for (int off = 1; off < 256; off <<= 1) {
    int add = (tid >= off) ? tmp[tid - off] : 0;
    __syncthreads();
    val += add;
    tmp[tid] = val;
    __syncthreads();
  }
  // val = inclusive scan; tmp[255] = block total
  if (tid == 255) base = atomicAdd(gcount, val);
  __syncthreads();
  if (i < N) {
    int excl = base + val - c;
    start[i] = excl;
    cursor[i] = excl;
  }
}

__global__ __launch_bounds__(256) void scatter_perm_kernel(
    const int* __restrict__ src, const int* __restrict__ dst,
    int* __restrict__ cursor, int* __restrict__ perm, int E) {
  int e = blockIdx.x * 256 + threadIdx.x;
  if (e < E) {
    int pos = atomicAdd(&cursor[dst[e]], 1);
    perm[pos] = src[e];  // store src node directly
  }
}

// One 32-lane group per node: acc = (1+eps)*feat[n] + sum feat[perm[j]]
__global__ __launch_bounds__(256) void gather_kernel(
    const float* __restrict__ feat, const float* __restrict__ eps,
    const int* __restrict__ start, const int* __restrict__ counts,
    const int* __restrict__ perm, float* __restrict__ out, int N) {
  int gid = blockIdx.x * 256 + threadIdx.x;
  int g = gid >> 5;
  int lane = gid & 31;
  if (g >= N) return;
  const float4* f4 = (const float4*)feat;
  float scale = 1.0f + eps[0];
  float4 acc = f4[(size_t)g * 32 + lane];
  acc.x *= scale; acc.y *= scale; acc.z *= scale; acc.w *= scale;
  int j = start[g];
  int end = j + counts[g];
  for (; j + 2 <= end; j += 2) {
    int p0 = perm[j];
    int p1 = perm[j + 1];
    float4 a = f4[(size_t)p0 * 32 + lane];
    float4 b = f4[(size_t)p1 * 32 + lane];
    acc.x += a.x; acc.y += a.y; acc.z += a.z; acc.w += a.w;
    acc.x += b.x; acc.y += b.y; acc.z += b.z; acc.w += b.w;
  }
  if (j < end) {
    int p0 = perm[j];
    float4 a = f4[(size_t)p0 * 32 + lane];
    acc.x += a.x; acc.y += a.y; acc.z += a.z; acc.w += a.w;
  }
  ((float4*)out)[(size_t)g * 32 + lane] = acc;
}

// ---------------- fallback atomic path ----------------

__global__ __launch_bounds__(256) void init_out_kernel(
    const float* __restrict__ feat, const float* __restrict__ eps,
    float* __restrict__ out, int n4) {
  int i = blockIdx.x * blockDim.x + threadIdx.x;
  if (i >= n4) return;
  float scale = 1.0f + eps[0];
  float4 v = ((const float4*)feat)[i];
  v.x *= scale; v.y *= scale; v.z *= scale; v.w *= scale;
  ((float4*)out)[i] = v;
}

__global__ __launch_bounds__(256) void scatter_add_kernel(
    const float* __restrict__ feat, const int* __restrict__ src,
    const int* __restrict__ dst, float* __restrict__ out, int E) {
  int gid = blockIdx.x * blockDim.x + threadIdx.x;
  int e = gid >> 5;
  int lane = gid & 31;
  if (e >= E) return;
  int s = src[e];
  int d = dst[e];
  float4 v = ((const float4*)(feat + (size_t)s * D))[lane];
  float* o = out + (size_t)d * D + lane * 4;
  unsafeAtomicAdd(o + 0, v.x);
  unsafeAtomicAdd(o + 1, v.y);
  unsafeAtomicAdd(o + 2, v.z);
  unsafeAtomicAdd(o + 3, v.w);
}

// ---------------- GEMM (in-place) ----------------

#define ROWS 64
__global__ __launch_bounds__(256) void gemm_inplace_kernel(
    float* __restrict__ out, const float* __restrict__ Wm,
    const float* __restrict__ bias, int N) {
  __shared__ float Ws[D * D];      // 64 KB
  __shared__ float xs[ROWS * D];   // 32 KB
  int tid = threadIdx.x;
  int base = blockIdx.x * ROWS;

  #pragma unroll
  for (int it = 0; it < 16; ++it) {
    int idx = tid + 256 * it;
    ((float4*)Ws)[idx] = ((const float4*)Wm)[idx];
  }
  #pragma unroll
  for (int it = 0; it < 8; ++it) {
    int idx = tid + 256 * it;
    int row = idx >> 5;
    int c4 = idx & 31;
    float4 v = make_float4(0.f, 0.f, 0.f, 0.f);
    if (base + row < N) v = ((const float4*)(out + (size_t)(base + row) * D))[c4];
    ((float4*)xs)[row * 32 + c4] = v;
  }
  __syncthreads();

  int tc = tid & 31;
  int tr = tid >> 5;
  float acc[8][4];
  #pragma unroll
  for (int r = 0; r < 8; ++r)
    #pragma unroll
    for (int i = 0; i < 4; ++i) acc[r][i] = 0.f;

  for (int k0 = 0; k0 < D; k0 += 4) {
    float4 f[8];
    #pragma unroll
    for (int r = 0; r < 8; ++r)
      f[r] = *(const float4*)&xs[(tr * 8 + r) * D + k0];
    float w[4][4];
    #pragma unroll
    for (int u = 0; u < 4; ++u)
      #pragma unroll
      for (int i = 0; i < 4; ++i)
        w[u][i] = Ws[(k0 + u) * D + tc + 32 * i];
    #pragma unroll
    for (int r = 0; r < 8; ++r)
      #pragma unroll
      for (int i = 0; i < 4; ++i) {
        acc[r][i] += f[r].x * w[0][i];
        acc[r][i] += f[r].y * w[1][i];
        acc[r][i] += f[r].z * w[2][i];
        acc[r][i] += f[r].w * w[3][i];
      }
  }

  float bv[4];
  #pragma unroll
  for (int i = 0; i < 4; ++i) bv[i] = bias[tc + 32 * i];

  #pragma unroll
  for (int r = 0; r < 8; ++r) {
    int row = base + tr * 8 + r;
    if (row < N) {
      #pragma unroll
      for (int i = 0; i < 4; ++i)
        out[(size_t)row * D + tc + 32 * i] = acc[r][i] + bv[i];
    }
  }
}

extern "C" void kernel_launch(void* const* d_in, const int* in_sizes, int n_in,
                              void* d_out, int out_size, void* d_ws, size_t ws_size,
                              hipStream_t stream) {
  const float* feat = (const float*)d_in[0];
  const float* Wm   = (const float*)d_in[1];
  const float* bias = (const float*)d_in[2];
  const float* eps  = (const float*)d_in[3];
  const int*   src  = (const int*)d_in[4];
  const int*   dst  = (const int*)d_in[5];
  float* out = (float*)d_out;

  int N = in_sizes[0] / D;   // 50000
  int E = in_sizes[4];       // 800000

  size_t needed = (size_t)(3 * N + 1 + E) * sizeof(int);

  if (ws_size >= needed) {
    int* counts = (int*)d_ws;        // N
    int* gcount = counts + N;        // 1
    int* start  = gcount + 1;        // N
    int* cursor = start + N;         // N
    int* perm   = cursor + N;        // E

    // zero counts + gcount (cursor/start/perm fully overwritten)
    hipMemsetAsync(counts, 0, (size_t)(N + 1) * sizeof(int), stream);

    hist_kernel<<<(E + 255) / 256, 256, 0, stream>>>(dst, counts, E);
    scan_kernel<<<(N + 255) / 256, 256, 0, stream>>>(counts, start, cursor, gcount, N);
    scatter_perm_kernel<<<(E + 255) / 256, 256, 0, stream>>>(src, dst, cursor, perm, E);

    int gthreads_blocks = (N * 32 + 255) / 256;
    gather_kernel<<<gthreads_blocks, 256, 0, stream>>>(feat, eps, start, counts, perm, out, N);
  } else {
    int n4 = (N * D) / 4;
    init_out_kernel<<<(n4 + 255) / 256, 256, 0, stream>>>(feat, eps, out, n4);
    long long total_threads = (long long)E * 32;
    int sblocks = (int)((total_threads + 255) / 256);
    scatter_add_kernel<<<sblocks, 256, 0, stream>>>(feat, src, dst, out, E);
  }

  int gblocks = (N + ROWS - 1) / ROWS;
  gemm_inplace_kernel<<<gblocks, 256, 0, stream>>>(out, Wm, bias, N);
}